// Round 15
// baseline (219.417 us; speedup 1.0000x reference)
//
#include <hip/hip_runtime.h>
#include <hip/hip_bf16.h>
#include <math.h>

#define TB 8
#define TT 2048
#define TD 64
#define TK 5
#define TPAD 12
#define EPSBN 1e-5f
#define UMAX 4096

#define ROWS 64          // mm1: output rows per block (4 waves x 16)
#define BAND 66          // ROWS + 2 halo
#define LROWS 198        // 3 bands

// mm2f geometry: 16 rows/block, 4 waves; wave = 16u x 16co
#define ROWS2 16
#define BAND2 18
#define LROWS2 54        // 3 bands
#define SH8   432        // LROWS2 * 8 short8 per buffer
#define BUFB  6912       // LROWS2*64*2 bytes per buffer

typedef __attribute__((ext_vector_type(8))) short short8;
typedef __attribute__((ext_vector_type(4))) float f32x4;

// ws layout (float offsets)
#define OFF_S     0
#define OFF_SBF   1048576
#define OFF_R     1572864
#define OFF_IDX   1581056
#define OFF_W     1581096
#define OFF_WT1   1581136
#define OFF_WT2   1599568
#define OFF_H1    1618000
// end 6860880 floats = 27.4 MB

// ---------------- fused: trend/seasonal (sliding window) + weight repack + r zero ----------------
__global__ __launch_bounds__(256) void k_trend(const float* __restrict__ x,
                                               float* __restrict__ out, float* __restrict__ s,
                                               __hip_bfloat16* __restrict__ sbf,
                                               const float* __restrict__ w1, const float* __restrict__ w2,
                                               __hip_bfloat16* __restrict__ wt1, __hip_bfloat16* __restrict__ wt2,
                                               float* __restrict__ r)
{
    if (blockIdx.x >= 256) {
        int d = (blockIdx.x - 256) * 256 + threadIdx.x;
        if (d < TB * 1024) r[d] = 0.f;             // zero autocorr accumulator (replay-safe)
        if (d < 36864) {
            int j = d & 7, l = (d >> 3) & 63, nt = (d >> 9) & 3, kb = d >> 11;
            int tap = kb >> 1, half = kb & 1;
            int co = nt * 16 + (l & 15);
            int ci = half * 32 + (l >> 4) * 8 + j;
            int src = (co * 64 + ci) * 9 + tap;
            wt1[d] = __float2bfloat16(w1[src]);
            wt2[d] = __float2bfloat16(w2[src]);
        }
        return;
    }
    int gid = blockIdx.x * 256 + threadIdx.x;      // 65536 threads
    int c = gid & 63;
    int tblk = (gid >> 6) & 127;
    int b = gid >> 13;
    int t0 = tblk * 16;
    const float* base = x + (size_t)b * TT * TD + c;
    float sum = 0.f;
    for (int tt = t0 - TPAD; tt <= t0 + TPAD; ++tt)
        if (tt >= 0 && tt < TT) sum += base[(size_t)tt * TD];
    size_t o = (size_t)b * TT * TD + (size_t)t0 * TD + c;
    #pragma unroll
    for (int i = 0; i < 16; ++i) {
        int t = t0 + i;
        int lo = t - TPAD; if (lo < 0) lo = 0;
        int hi = t + TPAD; if (hi > TT - 1) hi = TT - 1;
        float tr = sum / (float)(hi - lo + 1);
        float xv = base[(size_t)t * TD];
        out[o] = xv + tr;
        float sv = xv - tr;
        s[o] = sv;
        sbf[o] = __float2bfloat16(sv);
        int addt = t + TPAD + 1, subt = t - TPAD;
        if (addt < TT) sum += base[(size_t)addt * TD];
        if (subt >= 0) sum -= base[(size_t)subt * TD];
        o += TD;
    }
}

// ---------------- circular autocorrelation, LDS-tiled (f32 exact, XCD-bound) ----------------
// Block = 64 t-rows x 64 lags. Grid 4096: b = id&7, tchunk = (id>>3)&31, lagblk = id>>8.
// 256 thr = 16 cg(x4ch) x 4 t-stripes x 4 lag-subgroups(=waves, 16 lags each).
__global__ __launch_bounds__(256) void k_autocorr(const float* __restrict__ s, float* __restrict__ r)
{
    int id = blockIdx.x;
    int b = id & 7;
    int i0 = id >> 3;
    int tchunk = i0 & 31;
    int lagblk = i0 >> 5;                          // 0..15
    int t0 = tchunk * 64;
    int l0 = lagblk * 64 + 1;                      // lags l0..l0+63
    const float* sb = s + (size_t)b * TT * TD;
    __shared__ float A[64 * 64];
    __shared__ float W[127 * 64];

    // stage A: 64 rows (t0..t0+63), coalesced float4
    #pragma unroll
    for (int it = 0; it < 4; ++it) {
        int q = threadIdx.x + it * 256;
        int row = q >> 4, f4 = (q & 15) * 4;
        *(float4*)(A + row * 64 + f4) = *(const float4*)(sb + (size_t)(t0 + row) * TD + f4);
    }
    // stage W: 127 rows ((t0+l0+row) mod T)
    for (int q = threadIdx.x; q < 127 * 16; q += 256) {
        int row = q >> 4, f4 = (q & 15) * 4;
        int gr = t0 + l0 + row; if (gr >= TT) gr -= TT;   // max 3072-2048 < 2048
        *(float4*)(W + row * 64 + f4) = *(const float4*)(sb + (size_t)gr * TD + f4);
    }
    __syncthreads();

    int cg = (threadIdx.x & 15) * 4;               // channel offset
    int slot = threadIdx.x >> 4;                   // 0..15
    int lsub = slot >> 2;                          // wave id (16 lags per wave)
    int ts = slot & 3;                             // t-stripe (16 t each)
    int abase = ts * 16;
    int wbase = ts * 16 + lsub * 16;               // + step + j  (max 96+30=126)

    float acc[16];
    #pragma unroll
    for (int j = 0; j < 16; ++j) acc[j] = 0.f;
    float4 win[16];
    #pragma unroll
    for (int m = 0; m < 16; ++m) win[m] = *(const float4*)(W + (wbase + m) * 64 + cg);

    #pragma unroll
    for (int step = 0; step < 16; ++step) {
        float4 a = *(const float4*)(A + (abase + step) * 64 + cg);
        #pragma unroll
        for (int j = 0; j < 16; ++j) {
            float4 w = win[(step + j) & 15];
            acc[j] = fmaf(a.x, w.x, acc[j]);
            acc[j] = fmaf(a.y, w.y, acc[j]);
            acc[j] = fmaf(a.z, w.z, acc[j]);
            acc[j] = fmaf(a.w, w.w, acc[j]);
        }
        if (step < 15) win[step & 15] = *(const float4*)(W + (wbase + step + 16) * 64 + cg);
    }

    // per-wave butterfly: sum over 64 lanes (16 cg x 4 ts) for each of the wave's 16 lags
    int lane = threadIdx.x & 63;
    #pragma unroll
    for (int j = 0; j < 16; ++j) {
        float v = acc[j];
        #pragma unroll
        for (int mask = 32; mask; mask >>= 1) v += __shfl_xor(v, mask);
        if (lane == 0)
            atomicAdd(&r[(size_t)b * 1024 + (l0 - 1 + lsub * 16 + j)], v * (1.0f / 64.0f));
    }
}

// ---------------- top-5 with symmetric-pair expansion + softmax ----------------
__global__ __launch_bounds__(256) void k_topk(const float* __restrict__ r,
                                              int* __restrict__ selidx, float* __restrict__ selw)
{
    int b = blockIdx.x;
    __shared__ float v[1024];
    __shared__ float redv[256]; __shared__ int redi[256];
    __shared__ int s_idx[6]; __shared__ float s_val[6]; __shared__ int slots;
    for (int i = threadIdx.x; i < 1024; i += 256) v[i] = r[(size_t)b * 1024 + i];
    if (threadIdx.x == 0) slots = 0;
    __syncthreads();
    for (int round = 0; round < 5; ++round) {
        if (slots >= 5) break;
        float bv = -INFINITY; int bi = 1 << 30;
        for (int i = threadIdx.x; i < 1024; i += 256) {
            float val = v[i];
            if (val > bv) { bv = val; bi = i; }
        }
        redv[threadIdx.x] = bv; redi[threadIdx.x] = bi;
        __syncthreads();
        for (int off = 128; off; off >>= 1) {
            if (threadIdx.x < off) {
                float ov = redv[threadIdx.x + off]; int oi = redi[threadIdx.x + off];
                float mv = redv[threadIdx.x];       int mi = redi[threadIdx.x];
                if (ov > mv || (ov == mv && oi < mi)) { redv[threadIdx.x] = ov; redi[threadIdx.x] = oi; }
            }
            __syncthreads();
        }
        if (threadIdx.x == 0) {
            int lag = redi[0] + 1; float val = redv[0];
            s_idx[slots] = lag; s_val[slots] = val; slots++;
            if (slots < 5 && lag < 1024) { s_idx[slots] = 2048 - lag; s_val[slots] = val; slots++; }
            v[lag - 1] = -INFINITY;
        }
        __syncthreads();
    }
    if (threadIdx.x == 0) {
        float mx = -INFINITY;
        for (int i = 0; i < 5; ++i) mx = fmaxf(mx, s_val[i]);
        float e[5], sum = 0.f;
        for (int i = 0; i < 5; ++i) { e[i] = expf(s_val[i] - mx); sum += e[i]; }
        for (int i = 0; i < 5; ++i) { selidx[b * TK + i] = s_idx[i]; selw[b * TK + i] = e[i] / sum; }
    }
}

// ---------------- conv1: 4-wave blocks, wave = 16u x 64co; LDS halo + MFMA + BN1 + GELU ----------------
__global__ __launch_bounds__(256) void k_mm1(
    const short* __restrict__ s_bf, const short* __restrict__ wtp,
    const float* __restrict__ g1, const float* __restrict__ b1,
    const float* __restrict__ m1, const float* __restrict__ v1,
    const int* __restrict__ sel, __hip_bfloat16* __restrict__ h1)
{
    int b = blockIdx.z, k = blockIdx.y;
    int p = sel[b * TK + k];
    int cyc = (TT + p - 1) / p;
    int U = cyc * p;
    int u0 = blockIdx.x * ROWS;
    if (u0 >= U) return;
    __shared__ short As[LROWS * 64];

    const short* sb = s_bf + (size_t)b * TT * TD;
    for (int q = threadIdx.x; q < LROWS * 8; q += 256) {
        int row = q >> 3, ch = (q & 7) * 8;
        int band = row / BAND, i = row - band * BAND;
        int w = u0 + (band - 1) * p - 1 + i;
        int wc = min(max(w, 0), 2 * TT - 2);
        int v = (wc < TT) ? wc : (2 * TT - 2 - wc);
        int sr = (v + p) & (TT - 1);
        short8 d = *(const short8*)(sb + (size_t)sr * TD + ch);
        int off = (row * 128 + ch * 2) ^ ((row & 7) << 4);
        *(short8*)((char*)As + off) = d;
    }
    __syncthreads();

    int lane = threadIdx.x & 63;
    int wv = threadIdx.x >> 6;
    int lr = lane & 15;
    int kg = lane >> 4;
    int lu = wv * 16 + lr;
    int u = u0 + lu;
    bool inU = (u < U);
    int r = u / p, c = u - r * p;
    bool topf = (r == 0), botf = (r == cyc - 1), leftf = (c == 0), rightf = (c == p - 1);

    f32x4 acc[4] = {};
    short8 zero = {};
    #pragma unroll
    for (int kb = 0; kb < 18; ++kb) {
        const int tap = kb >> 1, half = kb & 1;
        const int dr = tap / 3 - 1, dc = tap % 3 - 1;
        int ldsrow = (dr + 1) * BAND + lu + 1 + dc;
        int off = (ldsrow * 128 + half * 64 + kg * 16) ^ ((ldsrow & 7) << 4);
        short8 a = *(const short8*)((const char*)As + off);
        bool valid = inU
                   && !(dr == -1 && topf) && !(dr == 1 && botf)
                   && !(dc == -1 && leftf) && !(dc == 1 && rightf);
        if (!valid) a = zero;
        #pragma unroll
        for (int nt = 0; nt < 4; ++nt) {
            short8 bq = *(const short8*)(wtp + (size_t)(kb * 4 + nt) * 512 + lane * 8);
            acc[nt] = __builtin_amdgcn_mfma_f32_16x16x32_bf16(a, bq, acc[nt], 0, 0, 0);
        }
    }
    __hip_bfloat16* ho = h1 + (size_t)(b * TK + k) * (UMAX * TD);
    #pragma unroll
    for (int nt = 0; nt < 4; ++nt) {
        int co = nt * 16 + lr;
        float scale = g1[co] * rsqrtf(v1[co] + EPSBN);
        float bias = b1[co] - m1[co] * scale;
        #pragma unroll
        for (int q = 0; q < 4; ++q) {
            int uo = u0 + wv * 16 + kg * 4 + q;
            if (uo < U) {
                float z = acc[nt][q] * scale + bias;
                float ge = 0.5f * z * (1.0f + erff(z * 0.70710678118654752f));
                ho[(size_t)uo * TD + co] = __float2bfloat16(ge);
            }
        }
    }
}

// ---------------- conv2 fused over k: 4-wave blocks (wave = 16u x 16co), dbuf LDS, no atomics ----------------
__global__ __launch_bounds__(256) void k_mm2f(
    const short* __restrict__ h1, const short* __restrict__ wtp,
    const float* __restrict__ s,
    const float* __restrict__ g2, const float* __restrict__ b2,
    const float* __restrict__ m2, const float* __restrict__ v2,
    const int* __restrict__ sel, const float* __restrict__ selw,
    float* __restrict__ out)
{
    int b = blockIdx.y;
    int u0 = blockIdx.x * ROWS2;                      // < 2048
    int tid = threadIdx.x;
    __shared__ short As[2 * LROWS2 * 64];

    int lane = tid & 63, wv = tid >> 6, lr = lane & 15, kg = lane >> 4;
    int u = u0 + lr;
    const float* sb = s + (size_t)b * TT * TD;

    f32x4 accT = {};
    float gacc[4] = {0.f, 0.f, 0.f, 0.f};
    short8 sreg[2];
    short8 zero = {};

    // prologue: stage phase 0 into buffer 0
    {
        int p0 = sel[b * TK];
        const short* hb = h1 + (size_t)(b * TK) * (UMAX * TD);
        #pragma unroll
        for (int it = 0; it < 2; ++it) {
            int q = tid + it * 256;
            if (q < SH8) {
                int row = q >> 3, ch = (q & 7) * 8;
                int band = row / BAND2, i = row - band * BAND2;
                int w = u0 + (band - 1) * p0 - 1 + i;
                int wc = min(max(w, 0), UMAX - 1);
                short8 d = *(const short8*)(hb + (size_t)wc * TD + ch);
                int off = (row * 128 + ch * 2) ^ ((row & 7) << 4);
                *(short8*)((char*)As + off) = d;
            }
        }
    }
    __syncthreads();

    for (int k = 0; k < TK; ++k) {
        int p = sel[b * TK + k];
        float wk = selw[b * TK + k];
        int cyc = (TT + p - 1) / p;
        // T14: issue next phase's global loads before this phase's compute
        if (k < TK - 1) {
            int pn = sel[b * TK + k + 1];
            const short* hb = h1 + (size_t)(b * TK + k + 1) * (UMAX * TD);
            #pragma unroll
            for (int it = 0; it < 2; ++it) {
                int q = tid + it * 256;
                if (q < SH8) {
                    int row = q >> 3, ch = (q & 7) * 8;
                    int band = row / BAND2, i = row - band * BAND2;
                    int w = u0 + (band - 1) * pn - 1 + i;
                    int wc = min(max(w, 0), UMAX - 1);
                    sreg[it] = *(const short8*)(hb + (size_t)wc * TD + ch);
                }
            }
        }
        // compute phase k from buffer k&1
        const char* Ab = (const char*)As + (k & 1) * BUFB;
        int r = u / p, c = u - r * p;
        bool topf = (r == 0), botf = (r == cyc - 1), leftf = (c == 0), rightf = (c == p - 1);
        f32x4 accP[2] = {};
        #pragma unroll
        for (int kb = 0; kb < 18; ++kb) {
            const int tap = kb >> 1, half = kb & 1;
            const int dr = tap / 3 - 1, dc = tap % 3 - 1;
            int ldsrow = (dr + 1) * BAND2 + lr + 1 + dc;
            int off = (ldsrow * 128 + half * 64 + kg * 16) ^ ((ldsrow & 7) << 4);
            short8 a = *(const short8*)(Ab + off);
            bool valid = !(dr == -1 && topf) && !(dr == 1 && botf)
                       && !(dc == -1 && leftf) && !(dc == 1 && rightf);
            if (!valid) a = zero;
            short8 bq = *(const short8*)(wtp + (size_t)(kb * 4 + wv) * 512 + lane * 8);
            accP[kb & 1] = __builtin_amdgcn_mfma_f32_16x16x32_bf16(a, bq, accP[kb & 1], 0, 0, 0);
        }
        #pragma unroll
        for (int e = 0; e < 4; ++e) accT[e] += wk * (accP[0][e] + accP[1][e]);
        #pragma unroll
        for (int q = 0; q < 4; ++q) {
            int uo = u0 + kg * 4 + q;
            int sr = (uo + p) & (TT - 1);
            gacc[q] = fmaf(wk, sb[(size_t)sr * TD + wv * 16 + lr], gacc[q]);
        }
        __syncthreads();
        if (k < TK - 1) {
            char* Aw = (char*)As + ((k + 1) & 1) * BUFB;
            #pragma unroll
            for (int it = 0; it < 2; ++it) {
                int q = tid + it * 256;
                if (q < SH8) {
                    int row = q >> 3, ch = (q & 7) * 8;
                    int off = (row * 128 + ch * 2) ^ ((row & 7) << 4);
                    *(short8*)(Aw + off) = sreg[it];
                }
            }
            __syncthreads();
        }
    }

    float* ob = out + (size_t)b * TT * TD;
    int co = wv * 16 + lr;
    float scale = g2[co] * rsqrtf(v2[co] + EPSBN);
    float bias = b2[co] - m2[co] * scale;
    #pragma unroll
    for (int q = 0; q < 4; ++q) {
        int uo = u0 + kg * 4 + q;
        size_t idx = (size_t)uo * TD + co;
        ob[idx] = ob[idx] + gacc[q] + scale * accT[q] + bias;
    }
}

extern "C" void kernel_launch(void* const* d_in, const int* in_sizes, int n_in,
                              void* d_out, int out_size, void* d_ws, size_t ws_size,
                              hipStream_t stream)
{
    const float* x  = (const float*)d_in[0];
    const float* w1 = (const float*)d_in[1];
    const float* w2 = (const float*)d_in[2];
    const float* g1 = (const float*)d_in[3];
    const float* b1 = (const float*)d_in[4];
    const float* m1 = (const float*)d_in[5];
    const float* v1 = (const float*)d_in[6];
    const float* g2 = (const float*)d_in[7];
    const float* b2 = (const float*)d_in[8];
    const float* m2 = (const float*)d_in[9];
    const float* v2 = (const float*)d_in[10];

    float* ws    = (float*)d_ws;
    float* s     = ws + OFF_S;
    __hip_bfloat16* sbf = (__hip_bfloat16*)(ws + OFF_SBF);
    float* r     = ws + OFF_R;
    int*   sel   = (int*)(ws + OFF_IDX);
    float* selw  = ws + OFF_W;
    __hip_bfloat16* wt1 = (__hip_bfloat16*)(ws + OFF_WT1);
    __hip_bfloat16* wt2 = (__hip_bfloat16*)(ws + OFF_WT2);
    __hip_bfloat16* h1  = (__hip_bfloat16*)(ws + OFF_H1);
    float* out   = (float*)d_out;

    k_trend   <<<dim3(400),         dim3(256), 0, stream>>>(x, out, s, sbf, w1, w2, wt1, wt2, r);
    k_autocorr<<<dim3(4096),        dim3(256), 0, stream>>>(s, r);
    k_topk    <<<dim3(TB),          dim3(256), 0, stream>>>(r, sel, selw);
    k_mm1     <<<dim3(64, TK, TB),  dim3(256), 0, stream>>>((const short*)sbf, (const short*)wt1,
                                                            g1, b1, m1, v1, sel, h1);
    k_mm2f    <<<dim3(128, TB),     dim3(256), 0, stream>>>((const short*)h1, (const short*)wt2, s,
                                                            g2, b2, m2, v2, sel, selw, out);
}

// Round 16
// 120.596 us; speedup vs baseline: 1.8194x; 1.8194x over previous
//
#include <hip/hip_runtime.h>
#include <hip/hip_bf16.h>
#include <math.h>

#define TB 8
#define TT 2048
#define TD 64
#define TK 5
#define TPAD 12
#define EPSBN 1e-5f
#define UMAX 4096

#define ROWS 64          // mm1: output rows per block (4 waves x 16)
#define BAND 66          // ROWS + 2 halo
#define LROWS 198        // 3 bands

// mm2f geometry: 16 rows/block, 4 waves; wave = 16u x 16co
#define ROWS2 16
#define BAND2 18
#define LROWS2 54        // 3 bands
#define SH8   432        // LROWS2 * 8 short8 per buffer
#define BUFB  6912       // LROWS2*64*2 bytes per buffer

#define RSTR 272         // padded reduction stride (4-way -> 2-way bank aliasing)

typedef __attribute__((ext_vector_type(8))) short short8;
typedef __attribute__((ext_vector_type(4))) float f32x4;

// ws layout (float offsets)
#define OFF_S     0
#define OFF_SBF   1048576
#define OFF_R     1572864
#define OFF_IDX   1581056
#define OFF_W     1581096
#define OFF_WT1   1581136
#define OFF_WT2   1599568
#define OFF_H1    1618000
// end 6860880 floats = 27.4 MB

// ---------------- fused: trend/seasonal (sliding window) + weight repack + r zero ----------------
__global__ __launch_bounds__(256) void k_trend(const float* __restrict__ x,
                                               float* __restrict__ out, float* __restrict__ s,
                                               __hip_bfloat16* __restrict__ sbf,
                                               const float* __restrict__ w1, const float* __restrict__ w2,
                                               __hip_bfloat16* __restrict__ wt1, __hip_bfloat16* __restrict__ wt2,
                                               float* __restrict__ r)
{
    if (blockIdx.x >= 256) {
        int d = (blockIdx.x - 256) * 256 + threadIdx.x;
        if (d < TB * 1024) r[d] = 0.f;             // zero autocorr accumulator (replay-safe)
        if (d < 36864) {
            int j = d & 7, l = (d >> 3) & 63, nt = (d >> 9) & 3, kb = d >> 11;
            int tap = kb >> 1, half = kb & 1;
            int co = nt * 16 + (l & 15);
            int ci = half * 32 + (l >> 4) * 8 + j;
            int src = (co * 64 + ci) * 9 + tap;
            wt1[d] = __float2bfloat16(w1[src]);
            wt2[d] = __float2bfloat16(w2[src]);
        }
        return;
    }
    int gid = blockIdx.x * 256 + threadIdx.x;      // 65536 threads
    int c = gid & 63;
    int tblk = (gid >> 6) & 127;
    int b = gid >> 13;
    int t0 = tblk * 16;
    const float* base = x + (size_t)b * TT * TD + c;
    float sum = 0.f;
    for (int tt = t0 - TPAD; tt <= t0 + TPAD; ++tt)
        if (tt >= 0 && tt < TT) sum += base[(size_t)tt * TD];
    size_t o = (size_t)b * TT * TD + (size_t)t0 * TD + c;
    #pragma unroll
    for (int i = 0; i < 16; ++i) {
        int t = t0 + i;
        int lo = t - TPAD; if (lo < 0) lo = 0;
        int hi = t + TPAD; if (hi > TT - 1) hi = TT - 1;
        float tr = sum / (float)(hi - lo + 1);
        float xv = base[(size_t)t * TD];
        out[o] = xv + tr;
        float sv = xv - tr;
        s[o] = sv;
        sbf[o] = __float2bfloat16(sv);
        int addt = t + TPAD + 1, subt = t - TPAD;
        if (addt < TT) sum += base[(size_t)addt * TD];
        if (subt >= 0) sum -= base[(size_t)subt * TD];
        o += TD;
    }
}

// ---------------- circular autocorrelation, lags 1..1024 (f32, XCD-bound, deep prefetch) ----------------
// 1-D grid 2048: b = id&7 (binds batch -> XCD), lag-group = (id>>3)&63, t-quarter = id>>9.
// 256 thr = 16 cg(x4ch) x 16 t-stripes(x32).
__global__ __launch_bounds__(256) void k_autocorr(const float* __restrict__ s, float* __restrict__ r)
{
    int id = blockIdx.x;
    int b = id & 7;
    int i0 = id >> 3;
    int l0 = (i0 & 63) * 16 + 1;                   // lags l0..l0+15
    int tq = i0 >> 6;                              // 0..3
    const float* sb = s + (size_t)b * TT * TD;
    int cg = (threadIdx.x & 15) * 4;
    int tg = threadIdx.x >> 4;
    int t0 = tq * 512 + tg * 32;
    const int RB = TD * 4;
    const int TTB = TT * TD * 4;
    float acc[16];
    #pragma unroll
    for (int j = 0; j < 16; ++j) acc[j] = 0.f;
    float4 win[16];
    int wi = t0 + l0; if (wi >= TT) wi -= TT;
    int woff = wi * RB + cg * 4;
    int aoff = t0 * RB + cg * 4;
    #pragma unroll
    for (int m = 0; m < 16; ++m) {
        win[m] = *(const float4*)((const char*)sb + woff);
        woff += RB; if (woff >= TTB) woff -= TTB;
    }
    float4 wpf = *(const float4*)((const char*)sb + woff);   // win staging reg (1 extra step deep)
    woff += RB; if (woff >= TTB) woff -= TTB;
    float4 a0 = *(const float4*)((const char*)sb + aoff); aoff += RB;   // 2-deep a pipeline
    float4 a1 = *(const float4*)((const char*)sb + aoff); aoff += RB;
    for (int it = 0; it < 2; ++it) {
        #pragma unroll
        for (int jj = 0; jj < 16; ++jj) {
            float4 a = a0;
            a0 = a1;
            a1 = *(const float4*)((const char*)sb + aoff);   // issued 2 steps ahead (benign over-read)
            aoff += RB;
            #pragma unroll
            for (int j = 0; j < 16; ++j) {
                float4 w = win[(jj + j) & 15];
                acc[j] = fmaf(a.x, w.x, acc[j]);
                acc[j] = fmaf(a.y, w.y, acc[j]);
                acc[j] = fmaf(a.z, w.z, acc[j]);
                acc[j] = fmaf(a.w, w.w, acc[j]);
            }
            win[jj] = wpf;                                   // fetched one step earlier
            wpf = *(const float4*)((const char*)sb + woff);
            woff += RB; if (woff >= TTB) woff -= TTB;
        }
    }
    __shared__ float red[16 * RSTR];
    #pragma unroll
    for (int j = 0; j < 16; ++j) red[j * RSTR + threadIdx.x] = acc[j];
    __syncthreads();
    int j = threadIdx.x >> 4, i = threadIdx.x & 15;
    float v = 0.f;
    #pragma unroll
    for (int m = 0; m < 16; ++m) v += red[j * RSTR + i + 16 * m];
    #pragma unroll
    for (int mask = 8; mask; mask >>= 1) v += __shfl_xor(v, mask);
    if (i == 0) atomicAdd(&r[(size_t)b * 1024 + (l0 - 1 + j)], v * (1.0f / 64.0f));
}

// ---------------- top-5 with symmetric-pair expansion + softmax ----------------
__global__ __launch_bounds__(256) void k_topk(const float* __restrict__ r,
                                              int* __restrict__ selidx, float* __restrict__ selw)
{
    int b = blockIdx.x;
    __shared__ float v[1024];
    __shared__ float redv[256]; __shared__ int redi[256];
    __shared__ int s_idx[6]; __shared__ float s_val[6]; __shared__ int slots;
    for (int i = threadIdx.x; i < 1024; i += 256) v[i] = r[(size_t)b * 1024 + i];
    if (threadIdx.x == 0) slots = 0;
    __syncthreads();
    for (int round = 0; round < 5; ++round) {
        if (slots >= 5) break;
        float bv = -INFINITY; int bi = 1 << 30;
        for (int i = threadIdx.x; i < 1024; i += 256) {
            float val = v[i];
            if (val > bv) { bv = val; bi = i; }
        }
        redv[threadIdx.x] = bv; redi[threadIdx.x] = bi;
        __syncthreads();
        for (int off = 128; off; off >>= 1) {
            if (threadIdx.x < off) {
                float ov = redv[threadIdx.x + off]; int oi = redi[threadIdx.x + off];
                float mv = redv[threadIdx.x];       int mi = redi[threadIdx.x];
                if (ov > mv || (ov == mv && oi < mi)) { redv[threadIdx.x] = ov; redi[threadIdx.x] = oi; }
            }
            __syncthreads();
        }
        if (threadIdx.x == 0) {
            int lag = redi[0] + 1; float val = redv[0];
            s_idx[slots] = lag; s_val[slots] = val; slots++;
            if (slots < 5 && lag < 1024) { s_idx[slots] = 2048 - lag; s_val[slots] = val; slots++; }
            v[lag - 1] = -INFINITY;
        }
        __syncthreads();
    }
    if (threadIdx.x == 0) {
        float mx = -INFINITY;
        for (int i = 0; i < 5; ++i) mx = fmaxf(mx, s_val[i]);
        float e[5], sum = 0.f;
        for (int i = 0; i < 5; ++i) { e[i] = expf(s_val[i] - mx); sum += e[i]; }
        for (int i = 0; i < 5; ++i) { selidx[b * TK + i] = s_idx[i]; selw[b * TK + i] = e[i] / sum; }
    }
}

// ---------------- conv1: 4-wave blocks, wave = 16u x 64co; LDS halo + MFMA + BN1 + GELU ----------------
__global__ __launch_bounds__(256) void k_mm1(
    const short* __restrict__ s_bf, const short* __restrict__ wtp,
    const float* __restrict__ g1, const float* __restrict__ b1,
    const float* __restrict__ m1, const float* __restrict__ v1,
    const int* __restrict__ sel, __hip_bfloat16* __restrict__ h1)
{
    int b = blockIdx.z, k = blockIdx.y;
    int p = sel[b * TK + k];
    int cyc = (TT + p - 1) / p;
    int U = cyc * p;
    int u0 = blockIdx.x * ROWS;
    if (u0 >= U) return;
    __shared__ short As[LROWS * 64];

    const short* sb = s_bf + (size_t)b * TT * TD;
    for (int q = threadIdx.x; q < LROWS * 8; q += 256) {
        int row = q >> 3, ch = (q & 7) * 8;
        int band = row / BAND, i = row - band * BAND;
        int w = u0 + (band - 1) * p - 1 + i;
        int wc = min(max(w, 0), 2 * TT - 2);
        int v = (wc < TT) ? wc : (2 * TT - 2 - wc);
        int sr = (v + p) & (TT - 1);
        short8 d = *(const short8*)(sb + (size_t)sr * TD + ch);
        int off = (row * 128 + ch * 2) ^ ((row & 7) << 4);
        *(short8*)((char*)As + off) = d;
    }
    __syncthreads();

    int lane = threadIdx.x & 63;
    int wv = threadIdx.x >> 6;
    int lr = lane & 15;
    int kg = lane >> 4;
    int lu = wv * 16 + lr;
    int u = u0 + lu;
    bool inU = (u < U);
    int r = u / p, c = u - r * p;
    bool topf = (r == 0), botf = (r == cyc - 1), leftf = (c == 0), rightf = (c == p - 1);

    f32x4 acc[4] = {};
    short8 zero = {};
    #pragma unroll
    for (int kb = 0; kb < 18; ++kb) {
        const int tap = kb >> 1, half = kb & 1;
        const int dr = tap / 3 - 1, dc = tap % 3 - 1;
        int ldsrow = (dr + 1) * BAND + lu + 1 + dc;
        int off = (ldsrow * 128 + half * 64 + kg * 16) ^ ((ldsrow & 7) << 4);
        short8 a = *(const short8*)((const char*)As + off);
        bool valid = inU
                   && !(dr == -1 && topf) && !(dr == 1 && botf)
                   && !(dc == -1 && leftf) && !(dc == 1 && rightf);
        if (!valid) a = zero;
        #pragma unroll
        for (int nt = 0; nt < 4; ++nt) {
            short8 bq = *(const short8*)(wtp + (size_t)(kb * 4 + nt) * 512 + lane * 8);
            acc[nt] = __builtin_amdgcn_mfma_f32_16x16x32_bf16(a, bq, acc[nt], 0, 0, 0);
        }
    }
    __hip_bfloat16* ho = h1 + (size_t)(b * TK + k) * (UMAX * TD);
    #pragma unroll
    for (int nt = 0; nt < 4; ++nt) {
        int co = nt * 16 + lr;
        float scale = g1[co] * rsqrtf(v1[co] + EPSBN);
        float bias = b1[co] - m1[co] * scale;
        #pragma unroll
        for (int q = 0; q < 4; ++q) {
            int uo = u0 + wv * 16 + kg * 4 + q;
            if (uo < U) {
                float z = acc[nt][q] * scale + bias;
                float ge = 0.5f * z * (1.0f + erff(z * 0.70710678118654752f));
                ho[(size_t)uo * TD + co] = __float2bfloat16(ge);
            }
        }
    }
}

// ---------------- conv2 fused over k: 4-wave blocks (wave = 16u x 16co), dbuf LDS, no atomics ----------------
__global__ __launch_bounds__(256) void k_mm2f(
    const short* __restrict__ h1, const short* __restrict__ wtp,
    const float* __restrict__ s,
    const float* __restrict__ g2, const float* __restrict__ b2,
    const float* __restrict__ m2, const float* __restrict__ v2,
    const int* __restrict__ sel, const float* __restrict__ selw,
    float* __restrict__ out)
{
    int b = blockIdx.y;
    int u0 = blockIdx.x * ROWS2;                      // < 2048
    int tid = threadIdx.x;
    __shared__ short As[2 * LROWS2 * 64];

    int lane = tid & 63, wv = tid >> 6, lr = lane & 15, kg = lane >> 4;
    int u = u0 + lr;
    const float* sb = s + (size_t)b * TT * TD;

    f32x4 accT = {};
    float gacc[4] = {0.f, 0.f, 0.f, 0.f};
    short8 sreg[2];
    short8 zero = {};

    // prologue: stage phase 0 into buffer 0
    {
        int p0 = sel[b * TK];
        const short* hb = h1 + (size_t)(b * TK) * (UMAX * TD);
        #pragma unroll
        for (int it = 0; it < 2; ++it) {
            int q = tid + it * 256;
            if (q < SH8) {
                int row = q >> 3, ch = (q & 7) * 8;
                int band = row / BAND2, i = row - band * BAND2;
                int w = u0 + (band - 1) * p0 - 1 + i;
                int wc = min(max(w, 0), UMAX - 1);
                short8 d = *(const short8*)(hb + (size_t)wc * TD + ch);
                int off = (row * 128 + ch * 2) ^ ((row & 7) << 4);
                *(short8*)((char*)As + off) = d;
            }
        }
    }
    __syncthreads();

    for (int k = 0; k < TK; ++k) {
        int p = sel[b * TK + k];
        float wk = selw[b * TK + k];
        int cyc = (TT + p - 1) / p;
        // T14: issue next phase's global loads before this phase's compute
        if (k < TK - 1) {
            int pn = sel[b * TK + k + 1];
            const short* hb = h1 + (size_t)(b * TK + k + 1) * (UMAX * TD);
            #pragma unroll
            for (int it = 0; it < 2; ++it) {
                int q = tid + it * 256;
                if (q < SH8) {
                    int row = q >> 3, ch = (q & 7) * 8;
                    int band = row / BAND2, i = row - band * BAND2;
                    int w = u0 + (band - 1) * pn - 1 + i;
                    int wc = min(max(w, 0), UMAX - 1);
                    sreg[it] = *(const short8*)(hb + (size_t)wc * TD + ch);
                }
            }
        }
        // compute phase k from buffer k&1
        const char* Ab = (const char*)As + (k & 1) * BUFB;
        int r = u / p, c = u - r * p;
        bool topf = (r == 0), botf = (r == cyc - 1), leftf = (c == 0), rightf = (c == p - 1);
        f32x4 accP[2] = {};
        #pragma unroll
        for (int kb = 0; kb < 18; ++kb) {
            const int tap = kb >> 1, half = kb & 1;
            const int dr = tap / 3 - 1, dc = tap % 3 - 1;
            int ldsrow = (dr + 1) * BAND2 + lr + 1 + dc;
            int off = (ldsrow * 128 + half * 64 + kg * 16) ^ ((ldsrow & 7) << 4);
            short8 a = *(const short8*)(Ab + off);
            bool valid = !(dr == -1 && topf) && !(dr == 1 && botf)
                       && !(dc == -1 && leftf) && !(dc == 1 && rightf);
            if (!valid) a = zero;
            short8 bq = *(const short8*)(wtp + (size_t)(kb * 4 + wv) * 512 + lane * 8);
            accP[kb & 1] = __builtin_amdgcn_mfma_f32_16x16x32_bf16(a, bq, accP[kb & 1], 0, 0, 0);
        }
        #pragma unroll
        for (int e = 0; e < 4; ++e) accT[e] += wk * (accP[0][e] + accP[1][e]);
        #pragma unroll
        for (int q = 0; q < 4; ++q) {
            int uo = u0 + kg * 4 + q;
            int sr = (uo + p) & (TT - 1);
            gacc[q] = fmaf(wk, sb[(size_t)sr * TD + wv * 16 + lr], gacc[q]);
        }
        __syncthreads();
        if (k < TK - 1) {
            char* Aw = (char*)As + ((k + 1) & 1) * BUFB;
            #pragma unroll
            for (int it = 0; it < 2; ++it) {
                int q = tid + it * 256;
                if (q < SH8) {
                    int row = q >> 3, ch = (q & 7) * 8;
                    int off = (row * 128 + ch * 2) ^ ((row & 7) << 4);
                    *(short8*)(Aw + off) = sreg[it];
                }
            }
            __syncthreads();
        }
    }

    float* ob = out + (size_t)b * TT * TD;
    int co = wv * 16 + lr;
    float scale = g2[co] * rsqrtf(v2[co] + EPSBN);
    float bias = b2[co] - m2[co] * scale;
    #pragma unroll
    for (int q = 0; q < 4; ++q) {
        int uo = u0 + kg * 4 + q;
        size_t idx = (size_t)uo * TD + co;
        ob[idx] = ob[idx] + gacc[q] + scale * accT[q] + bias;
    }
}

extern "C" void kernel_launch(void* const* d_in, const int* in_sizes, int n_in,
                              void* d_out, int out_size, void* d_ws, size_t ws_size,
                              hipStream_t stream)
{
    const float* x  = (const float*)d_in[0];
    const float* w1 = (const float*)d_in[1];
    const float* w2 = (const float*)d_in[2];
    const float* g1 = (const float*)d_in[3];
    const float* b1 = (const float*)d_in[4];
    const float* m1 = (const float*)d_in[5];
    const float* v1 = (const float*)d_in[6];
    const float* g2 = (const float*)d_in[7];
    const float* b2 = (const float*)d_in[8];
    const float* m2 = (const float*)d_in[9];
    const float* v2 = (const float*)d_in[10];

    float* ws    = (float*)d_ws;
    float* s     = ws + OFF_S;
    __hip_bfloat16* sbf = (__hip_bfloat16*)(ws + OFF_SBF);
    float* r     = ws + OFF_R;
    int*   sel   = (int*)(ws + OFF_IDX);
    float* selw  = ws + OFF_W;
    __hip_bfloat16* wt1 = (__hip_bfloat16*)(ws + OFF_WT1);
    __hip_bfloat16* wt2 = (__hip_bfloat16*)(ws + OFF_WT2);
    __hip_bfloat16* h1  = (__hip_bfloat16*)(ws + OFF_H1);
    float* out   = (float*)d_out;

    k_trend   <<<dim3(400),         dim3(256), 0, stream>>>(x, out, s, sbf, w1, w2, wt1, wt2, r);
    k_autocorr<<<dim3(2048),        dim3(256), 0, stream>>>(s, r);
    k_topk    <<<dim3(TB),          dim3(256), 0, stream>>>(r, sel, selw);
    k_mm1     <<<dim3(64, TK, TB),  dim3(256), 0, stream>>>((const short*)sbf, (const short*)wt1,
                                                            g1, b1, m1, v1, sel, h1);
    k_mm2f    <<<dim3(128, TB),     dim3(256), 0, stream>>>((const short*)h1, (const short*)wt2, s,
                                                            g2, b2, m2, v2, sel, selw, out);
}

// Round 17
// 117.679 us; speedup vs baseline: 1.8645x; 1.0248x over previous
//
#include <hip/hip_runtime.h>
#include <hip/hip_bf16.h>
#include <math.h>

#define TB 8
#define TT 2048
#define TD 64
#define TK 5
#define TPAD 12
#define EPSBN 1e-5f
#define UMAX 4096

#define ROWS 64          // mm1: output rows per block (4 waves x 16)
#define BAND 66          // ROWS + 2 halo
#define LROWS 198        // 3 bands

// mm2f geometry: 16 rows/block, 4 waves; wave = 16u x 16co
#define ROWS2 16
#define BAND2 18
#define LROWS2 54        // 3 bands
#define SH8   432        // LROWS2 * 8 short8 per buffer
#define BUFB  6912       // LROWS2*64*2 bytes per buffer

typedef __attribute__((ext_vector_type(8))) short short8;
typedef __attribute__((ext_vector_type(4))) float f32x4;

// ws layout (float offsets)
#define OFF_S     0
#define OFF_SBF   1048576
#define OFF_R     1572864
#define OFF_IDX   1581056
#define OFF_W     1581096
#define OFF_WT1   1581136
#define OFF_WT2   1599568
#define OFF_H1    1618000
// end 6860880 floats = 27.4 MB

// ---------------- fused: trend/seasonal (sliding window) + weight repack + r zero ----------------
__global__ __launch_bounds__(256) void k_trend(const float* __restrict__ x,
                                               float* __restrict__ out, float* __restrict__ s,
                                               __hip_bfloat16* __restrict__ sbf,
                                               const float* __restrict__ w1, const float* __restrict__ w2,
                                               __hip_bfloat16* __restrict__ wt1, __hip_bfloat16* __restrict__ wt2,
                                               float* __restrict__ r)
{
    if (blockIdx.x >= 256) {
        int d = (blockIdx.x - 256) * 256 + threadIdx.x;
        if (d < TB * 1024) r[d] = 0.f;             // zero autocorr accumulator (replay-safe)
        if (d < 36864) {
            int j = d & 7, l = (d >> 3) & 63, nt = (d >> 9) & 3, kb = d >> 11;
            int tap = kb >> 1, half = kb & 1;
            int co = nt * 16 + (l & 15);
            int ci = half * 32 + (l >> 4) * 8 + j;
            int src = (co * 64 + ci) * 9 + tap;
            wt1[d] = __float2bfloat16(w1[src]);
            wt2[d] = __float2bfloat16(w2[src]);
        }
        return;
    }
    int gid = blockIdx.x * 256 + threadIdx.x;      // 65536 threads
    int c = gid & 63;
    int tblk = (gid >> 6) & 127;
    int b = gid >> 13;
    int t0 = tblk * 16;
    const float* base = x + (size_t)b * TT * TD + c;
    float sum = 0.f;
    for (int tt = t0 - TPAD; tt <= t0 + TPAD; ++tt)
        if (tt >= 0 && tt < TT) sum += base[(size_t)tt * TD];
    size_t o = (size_t)b * TT * TD + (size_t)t0 * TD + c;
    #pragma unroll
    for (int i = 0; i < 16; ++i) {
        int t = t0 + i;
        int lo = t - TPAD; if (lo < 0) lo = 0;
        int hi = t + TPAD; if (hi > TT - 1) hi = TT - 1;
        float tr = sum / (float)(hi - lo + 1);
        float xv = base[(size_t)t * TD];
        out[o] = xv + tr;
        float sv = xv - tr;
        s[o] = sv;
        sbf[o] = __float2bfloat16(sv);
        int addt = t + TPAD + 1, subt = t - TPAD;
        if (addt < TT) sum += base[(size_t)addt * TD];
        if (subt >= 0) sum -= base[(size_t)subt * TD];
        o += TD;
    }
}

// ---------------- circular autocorrelation, LDS-tiled v2 (f32 exact, XCD-bound) ----------------
// Block = 64 t-rows x 64 lags. Grid 4096: b = id&7, tchunk = (id>>3)&31, lagblk = id>>8.
// 256 thr = 16 cg(x4ch) x 4 t-stripes x 4 waves (16 lags each).
// v2 fixes vs r15: parallel amortized epilogue (no serial shfl chains), 2-step prefetch
// slack on BOTH LDS streams (a0/a1 pair + wpf staging).
__global__ __launch_bounds__(256) void k_autocorr(const float* __restrict__ s, float* __restrict__ r)
{
    int id = blockIdx.x;
    int b = id & 7;
    int i0 = id >> 3;
    int tchunk = i0 & 31;
    int lagblk = i0 >> 5;                          // 0..15
    int t0 = tchunk * 64;
    int l0 = lagblk * 64 + 1;                      // lags l0..l0+63
    const float* sb = s + (size_t)b * TT * TD;
    __shared__ float A[64 * 64];
    __shared__ float W[127 * 64];

    // stage A: 64 rows (t0..t0+63), coalesced float4
    #pragma unroll
    for (int it = 0; it < 4; ++it) {
        int q = threadIdx.x + it * 256;
        int row = q >> 4, f4 = (q & 15) * 4;
        *(float4*)(A + row * 64 + f4) = *(const float4*)(sb + (size_t)(t0 + row) * TD + f4);
    }
    // stage W: 127 rows ((t0+l0+row) mod T)
    for (int q = threadIdx.x; q < 127 * 16; q += 256) {
        int row = q >> 4, f4 = (q & 15) * 4;
        int gr = t0 + l0 + row; if (gr >= TT) gr -= TT;   // < 2*TT always
        *(float4*)(W + row * 64 + f4) = *(const float4*)(sb + (size_t)gr * TD + f4);
    }
    __syncthreads();

    int cg = (threadIdx.x & 15) * 4;               // channel offset
    int slot = threadIdx.x >> 4;                   // 0..15
    int lsub = slot >> 2;                          // wave id (16 lags per wave)
    int ts = slot & 3;                             // t-stripe (16 t each)
    int abase = ts * 16;
    int wbase = ts * 16 + lsub * 16;               // consumed rows wbase..wbase+30 (max 126)

    float acc[16];
    #pragma unroll
    for (int j = 0; j < 16; ++j) acc[j] = 0.f;
    float4 win[16];
    #pragma unroll
    for (int m = 0; m < 16; ++m) win[m] = *(const float4*)(W + (wbase + m) * 64 + cg);
    float4 wpf = *(const float4*)(W + (wbase + 16) * 64 + cg);   // staged 1 extra step
    float4 a0 = *(const float4*)(A + (abase + 0) * 64 + cg);     // 2-deep a pipeline
    float4 a1 = *(const float4*)(A + (abase + 1) * 64 + cg);

    #pragma unroll
    for (int step = 0; step < 16; ++step) {
        float4 a = a0;
        a0 = a1;
        int ai = abase + step + 2; if (ai > 63) ai = 63;          // clamped loads are dead
        a1 = *(const float4*)(A + ai * 64 + cg);
        #pragma unroll
        for (int j = 0; j < 16; ++j) {
            float4 w = win[(step + j) & 15];
            acc[j] = fmaf(a.x, w.x, acc[j]);
            acc[j] = fmaf(a.y, w.y, acc[j]);
            acc[j] = fmaf(a.z, w.z, acc[j]);
            acc[j] = fmaf(a.w, w.w, acc[j]);
        }
        win[step & 15] = wpf;                                     // row wbase+16+step
        int wi2 = wbase + 17 + step; if (wi2 > 126) wi2 = 126;    // dead past step 13
        wpf = *(const float4*)(W + wi2 * 64 + cg);
    }

    // ---- parallel epilogue: red aliased onto W (all W reads complete) ----
    __syncthreads();
    float* red = W;                                // 64 combos x 65 + 256 partials = 4416 floats
    #pragma unroll
    for (int j = 0; j < 16; ++j)
        red[(lsub * 16 + j) * 65 + (threadIdx.x & 63)] = acc[j];
    __syncthreads();
    {
        int c2 = threadIdx.x & 63, part = threadIdx.x >> 6;
        float v = 0.f;
        #pragma unroll
        for (int m = 0; m < 16; ++m) v += red[c2 * 65 + part * 16 + m];
        red[4160 + part * 64 + c2] = v;
    }
    __syncthreads();
    if (threadIdx.x < 64) {
        float v = red[4160 + threadIdx.x] + red[4160 + 64 + threadIdx.x]
                + red[4160 + 128 + threadIdx.x] + red[4160 + 192 + threadIdx.x];
        atomicAdd(&r[(size_t)b * 1024 + lagblk * 64 + threadIdx.x], v * (1.0f / 64.0f));
    }
}

// ---------------- top-5 with symmetric-pair expansion + softmax ----------------
__global__ __launch_bounds__(256) void k_topk(const float* __restrict__ r,
                                              int* __restrict__ selidx, float* __restrict__ selw)
{
    int b = blockIdx.x;
    __shared__ float v[1024];
    __shared__ float redv[256]; __shared__ int redi[256];
    __shared__ int s_idx[6]; __shared__ float s_val[6]; __shared__ int slots;
    for (int i = threadIdx.x; i < 1024; i += 256) v[i] = r[(size_t)b * 1024 + i];
    if (threadIdx.x == 0) slots = 0;
    __syncthreads();
    for (int round = 0; round < 5; ++round) {
        if (slots >= 5) break;
        float bv = -INFINITY; int bi = 1 << 30;
        for (int i = threadIdx.x; i < 1024; i += 256) {
            float val = v[i];
            if (val > bv) { bv = val; bi = i; }
        }
        redv[threadIdx.x] = bv; redi[threadIdx.x] = bi;
        __syncthreads();
        for (int off = 128; off; off >>= 1) {
            if (threadIdx.x < off) {
                float ov = redv[threadIdx.x + off]; int oi = redi[threadIdx.x + off];
                float mv = redv[threadIdx.x];       int mi = redi[threadIdx.x];
                if (ov > mv || (ov == mv && oi < mi)) { redv[threadIdx.x] = ov; redi[threadIdx.x] = oi; }
            }
            __syncthreads();
        }
        if (threadIdx.x == 0) {
            int lag = redi[0] + 1; float val = redv[0];
            s_idx[slots] = lag; s_val[slots] = val; slots++;
            if (slots < 5 && lag < 1024) { s_idx[slots] = 2048 - lag; s_val[slots] = val; slots++; }
            v[lag - 1] = -INFINITY;
        }
        __syncthreads();
    }
    if (threadIdx.x == 0) {
        float mx = -INFINITY;
        for (int i = 0; i < 5; ++i) mx = fmaxf(mx, s_val[i]);
        float e[5], sum = 0.f;
        for (int i = 0; i < 5; ++i) { e[i] = expf(s_val[i] - mx); sum += e[i]; }
        for (int i = 0; i < 5; ++i) { selidx[b * TK + i] = s_idx[i]; selw[b * TK + i] = e[i] / sum; }
    }
}

// ---------------- conv1: 4-wave blocks, wave = 16u x 64co; LDS halo + MFMA + BN1 + GELU ----------------
__global__ __launch_bounds__(256) void k_mm1(
    const short* __restrict__ s_bf, const short* __restrict__ wtp,
    const float* __restrict__ g1, const float* __restrict__ b1,
    const float* __restrict__ m1, const float* __restrict__ v1,
    const int* __restrict__ sel, __hip_bfloat16* __restrict__ h1)
{
    int b = blockIdx.z, k = blockIdx.y;
    int p = sel[b * TK + k];
    int cyc = (TT + p - 1) / p;
    int U = cyc * p;
    int u0 = blockIdx.x * ROWS;
    if (u0 >= U) return;
    __shared__ short As[LROWS * 64];

    const short* sb = s_bf + (size_t)b * TT * TD;
    for (int q = threadIdx.x; q < LROWS * 8; q += 256) {
        int row = q >> 3, ch = (q & 7) * 8;
        int band = row / BAND, i = row - band * BAND;
        int w = u0 + (band - 1) * p - 1 + i;
        int wc = min(max(w, 0), 2 * TT - 2);
        int v = (wc < TT) ? wc : (2 * TT - 2 - wc);
        int sr = (v + p) & (TT - 1);
        short8 d = *(const short8*)(sb + (size_t)sr * TD + ch);
        int off = (row * 128 + ch * 2) ^ ((row & 7) << 4);
        *(short8*)((char*)As + off) = d;
    }
    __syncthreads();

    int lane = threadIdx.x & 63;
    int wv = threadIdx.x >> 6;
    int lr = lane & 15;
    int kg = lane >> 4;
    int lu = wv * 16 + lr;
    int u = u0 + lu;
    bool inU = (u < U);
    int r = u / p, c = u - r * p;
    bool topf = (r == 0), botf = (r == cyc - 1), leftf = (c == 0), rightf = (c == p - 1);

    f32x4 acc[4] = {};
    short8 zero = {};
    #pragma unroll
    for (int kb = 0; kb < 18; ++kb) {
        const int tap = kb >> 1, half = kb & 1;
        const int dr = tap / 3 - 1, dc = tap % 3 - 1;
        int ldsrow = (dr + 1) * BAND + lu + 1 + dc;
        int off = (ldsrow * 128 + half * 64 + kg * 16) ^ ((ldsrow & 7) << 4);
        short8 a = *(const short8*)((const char*)As + off);
        bool valid = inU
                   && !(dr == -1 && topf) && !(dr == 1 && botf)
                   && !(dc == -1 && leftf) && !(dc == 1 && rightf);
        if (!valid) a = zero;
        #pragma unroll
        for (int nt = 0; nt < 4; ++nt) {
            short8 bq = *(const short8*)(wtp + (size_t)(kb * 4 + nt) * 512 + lane * 8);
            acc[nt] = __builtin_amdgcn_mfma_f32_16x16x32_bf16(a, bq, acc[nt], 0, 0, 0);
        }
    }
    __hip_bfloat16* ho = h1 + (size_t)(b * TK + k) * (UMAX * TD);
    #pragma unroll
    for (int nt = 0; nt < 4; ++nt) {
        int co = nt * 16 + lr;
        float scale = g1[co] * rsqrtf(v1[co] + EPSBN);
        float bias = b1[co] - m1[co] * scale;
        #pragma unroll
        for (int q = 0; q < 4; ++q) {
            int uo = u0 + wv * 16 + kg * 4 + q;
            if (uo < U) {
                float z = acc[nt][q] * scale + bias;
                float ge = 0.5f * z * (1.0f + erff(z * 0.70710678118654752f));
                ho[(size_t)uo * TD + co] = __float2bfloat16(ge);
            }
        }
    }
}

// ---------------- conv2 fused over k: 4-wave blocks (wave = 16u x 16co), dbuf LDS, no atomics ----------------
__global__ __launch_bounds__(256) void k_mm2f(
    const short* __restrict__ h1, const short* __restrict__ wtp,
    const float* __restrict__ s,
    const float* __restrict__ g2, const float* __restrict__ b2,
    const float* __restrict__ m2, const float* __restrict__ v2,
    const int* __restrict__ sel, const float* __restrict__ selw,
    float* __restrict__ out)
{
    int b = blockIdx.y;
    int u0 = blockIdx.x * ROWS2;                      // < 2048
    int tid = threadIdx.x;
    __shared__ short As[2 * LROWS2 * 64];

    int lane = tid & 63, wv = tid >> 6, lr = lane & 15, kg = lane >> 4;
    int u = u0 + lr;
    const float* sb = s + (size_t)b * TT * TD;

    f32x4 accT = {};
    float gacc[4] = {0.f, 0.f, 0.f, 0.f};
    short8 sreg[2];
    short8 zero = {};

    // prologue: stage phase 0 into buffer 0
    {
        int p0 = sel[b * TK];
        const short* hb = h1 + (size_t)(b * TK) * (UMAX * TD);
        #pragma unroll
        for (int it = 0; it < 2; ++it) {
            int q = tid + it * 256;
            if (q < SH8) {
                int row = q >> 3, ch = (q & 7) * 8;
                int band = row / BAND2, i = row - band * BAND2;
                int w = u0 + (band - 1) * p0 - 1 + i;
                int wc = min(max(w, 0), UMAX - 1);
                short8 d = *(const short8*)(hb + (size_t)wc * TD + ch);
                int off = (row * 128 + ch * 2) ^ ((row & 7) << 4);
                *(short8*)((char*)As + off) = d;
            }
        }
    }
    __syncthreads();

    for (int k = 0; k < TK; ++k) {
        int p = sel[b * TK + k];
        float wk = selw[b * TK + k];
        int cyc = (TT + p - 1) / p;
        // T14: issue next phase's global loads before this phase's compute
        if (k < TK - 1) {
            int pn = sel[b * TK + k + 1];
            const short* hb = h1 + (size_t)(b * TK + k + 1) * (UMAX * TD);
            #pragma unroll
            for (int it = 0; it < 2; ++it) {
                int q = tid + it * 256;
                if (q < SH8) {
                    int row = q >> 3, ch = (q & 7) * 8;
                    int band = row / BAND2, i = row - band * BAND2;
                    int w = u0 + (band - 1) * pn - 1 + i;
                    int wc = min(max(w, 0), UMAX - 1);
                    sreg[it] = *(const short8*)(hb + (size_t)wc * TD + ch);
                }
            }
        }
        // compute phase k from buffer k&1
        const char* Ab = (const char*)As + (k & 1) * BUFB;
        int r = u / p, c = u - r * p;
        bool topf = (r == 0), botf = (r == cyc - 1), leftf = (c == 0), rightf = (c == p - 1);
        f32x4 accP[2] = {};
        #pragma unroll
        for (int kb = 0; kb < 18; ++kb) {
            const int tap = kb >> 1, half = kb & 1;
            const int dr = tap / 3 - 1, dc = tap % 3 - 1;
            int ldsrow = (dr + 1) * BAND2 + lr + 1 + dc;
            int off = (ldsrow * 128 + half * 64 + kg * 16) ^ ((ldsrow & 7) << 4);
            short8 a = *(const short8*)(Ab + off);
            bool valid = !(dr == -1 && topf) && !(dr == 1 && botf)
                       && !(dc == -1 && leftf) && !(dc == 1 && rightf);
            if (!valid) a = zero;
            short8 bq = *(const short8*)(wtp + (size_t)(kb * 4 + wv) * 512 + lane * 8);
            accP[kb & 1] = __builtin_amdgcn_mfma_f32_16x16x32_bf16(a, bq, accP[kb & 1], 0, 0, 0);
        }
        #pragma unroll
        for (int e = 0; e < 4; ++e) accT[e] += wk * (accP[0][e] + accP[1][e]);
        #pragma unroll
        for (int q = 0; q < 4; ++q) {
            int uo = u0 + kg * 4 + q;
            int sr = (uo + p) & (TT - 1);
            gacc[q] = fmaf(wk, sb[(size_t)sr * TD + wv * 16 + lr], gacc[q]);
        }
        __syncthreads();
        if (k < TK - 1) {
            char* Aw = (char*)As + ((k + 1) & 1) * BUFB;
            #pragma unroll
            for (int it = 0; it < 2; ++it) {
                int q = tid + it * 256;
                if (q < SH8) {
                    int row = q >> 3, ch = (q & 7) * 8;
                    int off = (row * 128 + ch * 2) ^ ((row & 7) << 4);
                    *(short8*)(Aw + off) = sreg[it];
                }
            }
            __syncthreads();
        }
    }

    float* ob = out + (size_t)b * TT * TD;
    int co = wv * 16 + lr;
    float scale = g2[co] * rsqrtf(v2[co] + EPSBN);
    float bias = b2[co] - m2[co] * scale;
    #pragma unroll
    for (int q = 0; q < 4; ++q) {
        int uo = u0 + kg * 4 + q;
        size_t idx = (size_t)uo * TD + co;
        ob[idx] = ob[idx] + gacc[q] + scale * accT[q] + bias;
    }
}

extern "C" void kernel_launch(void* const* d_in, const int* in_sizes, int n_in,
                              void* d_out, int out_size, void* d_ws, size_t ws_size,
                              hipStream_t stream)
{
    const float* x  = (const float*)d_in[0];
    const float* w1 = (const float*)d_in[1];
    const float* w2 = (const float*)d_in[2];
    const float* g1 = (const float*)d_in[3];
    const float* b1 = (const float*)d_in[4];
    const float* m1 = (const float*)d_in[5];
    const float* v1 = (const float*)d_in[6];
    const float* g2 = (const float*)d_in[7];
    const float* b2 = (const float*)d_in[8];
    const float* m2 = (const float*)d_in[9];
    const float* v2 = (const float*)d_in[10];

    float* ws    = (float*)d_ws;
    float* s     = ws + OFF_S;
    __hip_bfloat16* sbf = (__hip_bfloat16*)(ws + OFF_SBF);
    float* r     = ws + OFF_R;
    int*   sel   = (int*)(ws + OFF_IDX);
    float* selw  = ws + OFF_W;
    __hip_bfloat16* wt1 = (__hip_bfloat16*)(ws + OFF_WT1);
    __hip_bfloat16* wt2 = (__hip_bfloat16*)(ws + OFF_WT2);
    __hip_bfloat16* h1  = (__hip_bfloat16*)(ws + OFF_H1);
    float* out   = (float*)d_out;

    k_trend   <<<dim3(400),         dim3(256), 0, stream>>>(x, out, s, sbf, w1, w2, wt1, wt2, r);
    k_autocorr<<<dim3(4096),        dim3(256), 0, stream>>>(s, r);
    k_topk    <<<dim3(TB),          dim3(256), 0, stream>>>(r, sel, selw);
    k_mm1     <<<dim3(64, TK, TB),  dim3(256), 0, stream>>>((const short*)sbf, (const short*)wt1,
                                                            g1, b1, m1, v1, sel, h1);
    k_mm2f    <<<dim3(128, TB),     dim3(256), 0, stream>>>((const short*)h1, (const short*)wt2, s,
                                                            g2, b2, m2, v2, sel, selw, out);
}